// Round 1
// baseline (661.778 us; speedup 1.0000x reference)
//
#include <hip/hip_runtime.h>
#include <hip/hip_bf16.h>
#include <math.h>

typedef float floatx4 __attribute__((ext_vector_type(4)));
typedef __bf16 bf16x8 __attribute__((ext_vector_type(8)));
typedef unsigned short ushort_t;

__device__ __forceinline__ float bf2f(ushort_t u) {
    union { unsigned int i; float f; } v; v.i = ((unsigned int)u) << 16; return v.f;
}
__device__ __forceinline__ ushort_t f2bf(float f) {
    union { float f; unsigned int i; } v; v.f = f;
    unsigned int i = v.i;
    return (ushort_t)((i + 0x7FFFu + ((i >> 16) & 1u)) >> 16);  // RNE, inputs finite
}
__device__ __forceinline__ unsigned int pack2(float a, float b) {
    return (unsigned int)f2bf(a) | ((unsigned int)f2bf(b) << 16);
}
__device__ __forceinline__ floatx4 mfma16(bf16x8 a, bf16x8 b, floatx4 c) {
    return __builtin_amdgcn_mfma_f32_16x16x32_bf16(a, b, c, 0, 0, 0);
}

// ---------------- Weight transpose+convert: W (2048x2048 fp32, KxN) -> Wt (NxK bf16)
__global__ void k_wtrans(const float* __restrict__ w0, const float* __restrict__ w1,
                         const float* __restrict__ w2, const float* __restrict__ w3,
                         const float* __restrict__ w4,
                         ushort_t* t0, ushort_t* t1, ushort_t* t2, ushort_t* t3, ushort_t* t4) {
    __shared__ float tile[32][33];
    int z = blockIdx.z;
    const float* W = z == 0 ? w0 : z == 1 ? w1 : z == 2 ? w2 : z == 3 ? w3 : w4;
    ushort_t* T    = z == 0 ? t0 : z == 1 ? t1 : z == 2 ? t2 : z == 3 ? t3 : t4;
    int n0 = blockIdx.x * 32, k0 = blockIdx.y * 32;
    int tx = threadIdx.x & 31, ty = threadIdx.x >> 5;  // ty 0..7
#pragma unroll
    for (int i = 0; i < 4; i++) {
        int row = ty + i * 8;
        tile[row][tx] = W[(size_t)(k0 + row) * 2048 + n0 + tx];
    }
    __syncthreads();
#pragma unroll
    for (int i = 0; i < 4; i++) {
        int row = ty + i * 8;
        T[(size_t)(n0 + row) * 2048 + k0 + tx] = f2bf(tile[tx][row]);
    }
}

// ---------------- lv (3200x2048 bf16, [b*200+t][h]) -> lvT ([b][h][t] padded t->224, zeros)
__global__ void k_vtrans(const ushort_t* __restrict__ lv, ushort_t* __restrict__ lvT) {
    __shared__ ushort_t tile[32][33];
    int n0 = blockIdx.x * 32;   // H tile
    int t0 = blockIdx.y * 32;   // token tile (224 total)
    int b = blockIdx.z;
    int tx = threadIdx.x & 31, ty = threadIdx.x >> 5;
#pragma unroll
    for (int i = 0; i < 4; i++) {
        int row = ty + i * 8;
        int tk = t0 + row;
        ushort_t v = 0;
        if (tk < 200) v = lv[(size_t)(b * 200 + tk) * 2048 + n0 + tx];
        tile[row][tx] = v;
    }
    __syncthreads();
#pragma unroll
    for (int i = 0; i < 4; i++) {
        int row = ty + i * 8;
        lvT[((size_t)b * 2048 + n0 + row) * 224 + t0 + tx] = tile[tx][row];
    }
}

// ---------------- Batched projection GEMM: C[3200x2048] = A(fp32) @ Wt^T + bias, bf16 out
// 128x128 tile, BK=32, 4 waves each 64x64 (4x4 frags of 16x16x32 bf16 MFMA)
__global__ __launch_bounds__(256) void k_gemm(
    const float* A0, const float* A1, const float* A2, const float* A3, const float* A4,
    const ushort_t* W0, const ushort_t* W1, const ushort_t* W2, const ushort_t* W3, const ushort_t* W4,
    const float* B0, const float* B1, const float* B2, const float* B3, const float* B4,
    ushort_t* C0, ushort_t* C1, ushort_t* C2, ushort_t* C3, ushort_t* C4) {
    int z = blockIdx.z;
    const float* A     = z == 0 ? A0 : z == 1 ? A1 : z == 2 ? A2 : z == 3 ? A3 : A4;
    const ushort_t* Wt = z == 0 ? W0 : z == 1 ? W1 : z == 2 ? W2 : z == 3 ? W3 : W4;
    const float* bias  = z == 0 ? B0 : z == 1 ? B1 : z == 2 ? B2 : z == 3 ? B3 : B4;
    ushort_t* C        = z == 0 ? C0 : z == 1 ? C1 : z == 2 ? C2 : z == 3 ? C3 : C4;

    const int K = 2048;
    int m0 = blockIdx.x * 128, n0 = blockIdx.y * 128;
    __shared__ ushort_t As[128 * 40];  // row stride 40 (+8 pad) -> conflict-free b128 reads
    __shared__ ushort_t Bs[128 * 40];
    int tid = threadIdx.x;
    int lane = tid & 63, w = tid >> 6;
    int quad = lane >> 4, col = lane & 15;
    int wr = w >> 1, wc = w & 1;

    // staging: 512 chunks of 8 elems (4 chunks/row), 2 per thread
    int c0i = tid, c1i = tid + 256;
    int ar0 = c0i >> 2, ak0 = (c0i & 3) * 8;
    int ar1 = c1i >> 2, ak1 = (c1i & 3) * 8;
    const float* Ag0 = A + (size_t)(m0 + ar0) * K + ak0;
    const float* Ag1 = A + (size_t)(m0 + ar1) * K + ak1;
    const ushort_t* Bg0 = Wt + (size_t)(n0 + ar0) * K + ak0;
    const ushort_t* Bg1 = Wt + (size_t)(n0 + ar1) * K + ak1;

    int aoff[4], boff[4];
#pragma unroll
    for (int i = 0; i < 4; i++) {
        aoff[i] = (wr * 64 + i * 16 + col) * 40 + quad * 8;
        boff[i] = (wc * 64 + i * 16 + col) * 40 + quad * 8;
    }

    floatx4 acc[4][4] = {};

    for (int k0 = 0; k0 < K; k0 += 32) {
        floatx4 fa00 = *(const floatx4*)(Ag0 + k0);
        floatx4 fa01 = *(const floatx4*)(Ag0 + k0 + 4);
        floatx4 fa10 = *(const floatx4*)(Ag1 + k0);
        floatx4 fa11 = *(const floatx4*)(Ag1 + k0 + 4);
        uint4 vb0 = *(const uint4*)(Bg0 + k0);
        uint4 vb1 = *(const uint4*)(Bg1 + k0);
        uint4 va0, va1;
        va0.x = pack2(fa00[0], fa00[1]); va0.y = pack2(fa00[2], fa00[3]);
        va0.z = pack2(fa01[0], fa01[1]); va0.w = pack2(fa01[2], fa01[3]);
        va1.x = pack2(fa10[0], fa10[1]); va1.y = pack2(fa10[2], fa10[3]);
        va1.z = pack2(fa11[0], fa11[1]); va1.w = pack2(fa11[2], fa11[3]);
        __syncthreads();  // previous compute done before overwrite
        *(uint4*)&As[ar0 * 40 + ak0] = va0;
        *(uint4*)&As[ar1 * 40 + ak1] = va1;
        *(uint4*)&Bs[ar0 * 40 + ak0] = vb0;
        *(uint4*)&Bs[ar1 * 40 + ak1] = vb1;
        __syncthreads();
        bf16x8 af[4], bfr[4];
#pragma unroll
        for (int i = 0; i < 4; i++) af[i] = *(const bf16x8*)&As[aoff[i]];
#pragma unroll
        for (int i = 0; i < 4; i++) bfr[i] = *(const bf16x8*)&Bs[boff[i]];
#pragma unroll
        for (int mi = 0; mi < 4; mi++)
#pragma unroll
            for (int ni = 0; ni < 4; ni++)
                acc[mi][ni] = mfma16(af[mi], bfr[ni], acc[mi][ni]);
    }

#pragma unroll
    for (int ni = 0; ni < 4; ni++) {
        int n = n0 + wc * 64 + ni * 16 + col;
        float bv = bias[n];
#pragma unroll
        for (int mi = 0; mi < 4; mi++) {
#pragma unroll
            for (int r = 0; r < 4; r++) {
                int m = m0 + wr * 64 + mi * 16 + quad * 4 + r;
                C[(size_t)m * 2048 + n] = f2bf(acc[mi][ni][r] + bv);
            }
        }
    }
}

// ---------------- Scores + softmax -> attn (bf16, [b][200 rows][224 cols], cols>=200 zero)
// block = 16 query rows x 224 keys; 4 waves split 14 key-frags
__global__ __launch_bounds__(256) void k_scores(
    const ushort_t* __restrict__ lq, const ushort_t* __restrict__ lk,
    const ushort_t* __restrict__ lloc, const ushort_t* __restrict__ kloc,
    const float* __restrict__ param, ushort_t* __restrict__ attn) {
    int qt = blockIdx.x;  // 0..12
    int b = blockIdx.y;   // 0..15
    int tid = threadIdx.x;
    int lane = tid & 63, w = tid >> 6;
    int quad = lane >> 4, col = lane & 15;
    int aq = qt * 16 + col; if (aq > 199) aq = 199;
    size_t gq = (size_t)(b * 200 + aq) * 2048;
    size_t gk[4];
#pragma unroll
    for (int i = 0; i < 4; i++) {
        int key = (w + 4 * i) * 16 + col;
        if (key > 199) key = 199;
        gk[i] = (size_t)(b * 200 + key) * 2048;
    }
    floatx4 acc[4] = {};

    for (int k0 = 0; k0 < 2048; k0 += 32) {
        int ko = k0 + quad * 8;
        bf16x8 lqv = *(const bf16x8*)(lq + gq + ko);
        bf16x8 llv = *(const bf16x8*)(lloc + gq + ko);
        floatx4 p0 = *(const floatx4*)(param + gq + ko);
        floatx4 p1 = *(const floatx4*)(param + gq + ko + 4);
        bf16x8 q1, q2;
#pragma unroll
        for (int j = 0; j < 4; j++) {
            q1[j]     = (__bf16)((float)lqv[j] + p0[j]);
            q1[j + 4] = (__bf16)((float)lqv[j + 4] + p1[j]);
            q2[j]     = (__bf16)((float)lqv[j] + (float)llv[j]);
            q2[j + 4] = (__bf16)((float)lqv[j + 4] + (float)llv[j + 4]);
        }
#pragma unroll
        for (int i = 0; i < 4; i++) {
            if (w + 4 * i < 14) {
                bf16x8 kv = *(const bf16x8*)(lk + gk[i] + ko);
                bf16x8 kl = *(const bf16x8*)(kloc + gk[i] + ko);
                acc[i] = mfma16(q1, kv, acc[i]);
                acc[i] = mfma16(q2, kl, acc[i]);
            }
        }
    }

    __shared__ float sc[16][224];
    const float scale = 0.022097086912079608f;  // 1/sqrt(2048)
#pragma unroll
    for (int i = 0; i < 4; i++) {
        int kf = w + 4 * i;
        if (kf < 14) {
#pragma unroll
            for (int r = 0; r < 4; r++) sc[quad * 4 + r][kf * 16 + col] = acc[i][r] * scale;
        }
    }
    __syncthreads();

    int r = tid >> 4, c16 = tid & 15;  // row r handled by 16 lanes of one wave-quad
    int qrow = qt * 16 + r;
    float ev[14];
    float mx = -1e30f;
#pragma unroll
    for (int j = 0; j < 14; j++) {
        int cc = c16 * 14 + j;
        float v = (cc < 200) ? sc[r][cc] : -1e30f;
        ev[j] = v;
        mx = fmaxf(mx, v);
    }
#pragma unroll
    for (int m = 1; m < 16; m <<= 1) mx = fmaxf(mx, __shfl_xor(mx, m, 16));
    float s = 0.f;
#pragma unroll
    for (int j = 0; j < 14; j++) {
        float e = __expf(ev[j] - mx);
        ev[j] = e;
        s += e;
    }
#pragma unroll
    for (int m = 1; m < 16; m <<= 1) s += __shfl_xor(s, m, 16);
    float rs = 1.0f / s;
    if (qrow < 200) {
        ushort_t* arow = attn + (size_t)(b * 200 + qrow) * 224;
#pragma unroll
        for (int j = 0; j < 14; j++) arow[c16 * 14 + j] = f2bf(ev[j] * rs);
    }
}

// ---------------- out[b][m][n] = attn[b][m][:] @ lv  (via lvT), fp32 out
__global__ __launch_bounds__(256) void k_pv(const ushort_t* __restrict__ attn,
                                            const ushort_t* __restrict__ lvT,
                                            float* __restrict__ out) {
    int nt = blockIdx.x;  // 0..15 (128 cols each)
    int qt = blockIdx.y;  // 0..12 (16 rows each)
    int b = blockIdx.z;
    int tid = threadIdx.x, lane = tid & 63, w = tid >> 6;
    int quad = lane >> 4, col = lane & 15;
    int aq = qt * 16 + col; if (aq > 199) aq = 199;
    const ushort_t* arow = attn + (size_t)(b * 200 + aq) * 224;
    int nbase = nt * 128 + w * 32;
    const ushort_t* bp0 = lvT + ((size_t)b * 2048 + nbase + col) * 224;
    const ushort_t* bp1 = lvT + ((size_t)b * 2048 + nbase + 16 + col) * 224;
    floatx4 acc[2] = {};
#pragma unroll
    for (int k0 = 0; k0 < 224; k0 += 32) {
        int ko = k0 + quad * 8;
        bf16x8 av = *(const bf16x8*)(arow + ko);
        bf16x8 b0 = *(const bf16x8*)(bp0 + ko);
        bf16x8 b1 = *(const bf16x8*)(bp1 + ko);
        acc[0] = mfma16(av, b0, acc[0]);
        acc[1] = mfma16(av, b1, acc[1]);
    }
#pragma unroll
    for (int f = 0; f < 2; f++) {
        int n = nbase + f * 16 + col;
#pragma unroll
        for (int r = 0; r < 4; r++) {
            int m = qt * 16 + quad * 4 + r;
            if (m < 200) out[(size_t)(b * 200 + m) * 2048 + n] = acc[f][r];
        }
    }
}

extern "C" void kernel_launch(void* const* d_in, const int* in_sizes, int n_in,
                              void* d_out, int out_size, void* d_ws, size_t ws_size,
                              hipStream_t stream) {
    (void)in_sizes; (void)n_in; (void)out_size; (void)ws_size;
    const float* q    = (const float*)d_in[0];
    const float* k    = (const float*)d_in[1];
    const float* v    = (const float*)d_in[2];
    const float* loc  = (const float*)d_in[3];
    const float* Wq   = (const float*)d_in[4];
    const float* bq   = (const float*)d_in[5];
    const float* Wk   = (const float*)d_in[6];
    const float* bk   = (const float*)d_in[7];
    const float* Wv   = (const float*)d_in[8];
    const float* bv   = (const float*)d_in[9];
    const float* Wloc = (const float*)d_in[10];
    const float* bloc = (const float*)d_in[11];
    const float* Wlk  = (const float*)d_in[12];
    const float* blk  = (const float*)d_in[13];
    const float* param = (const float*)d_in[14];
    float* out = (float*)d_out;

    // workspace layout (~124 MB)
    size_t off = 0;
    auto nxt = [&](size_t bytes) {
        void* p = (char*)d_ws + off;
        off += (bytes + 255) & ~(size_t)255;
        return p;
    };
    ushort_t* wt[5];
    for (int i = 0; i < 5; i++) wt[i] = (ushort_t*)nxt(2048ull * 2048 * 2);
    ushort_t* lqp   = (ushort_t*)nxt(3200ull * 2048 * 2);
    ushort_t* lkp   = (ushort_t*)nxt(3200ull * 2048 * 2);
    ushort_t* lvp   = (ushort_t*)nxt(3200ull * 2048 * 2);
    ushort_t* llocp = (ushort_t*)nxt(3200ull * 2048 * 2);
    ushort_t* klocp = (ushort_t*)nxt(3200ull * 2048 * 2);
    ushort_t* lvT   = (ushort_t*)nxt(16ull * 2048 * 224 * 2);
    ushort_t* attn  = (ushort_t*)nxt(16ull * 200 * 224 * 2);

    k_wtrans<<<dim3(64, 64, 5), 256, 0, stream>>>(Wq, Wk, Wv, Wloc, Wlk,
                                                  wt[0], wt[1], wt[2], wt[3], wt[4]);
    k_gemm<<<dim3(25, 16, 5), 256, 0, stream>>>(q, k, v, loc, loc,
                                                wt[0], wt[1], wt[2], wt[3], wt[4],
                                                bq, bk, bv, bloc, blk,
                                                lqp, lkp, lvp, llocp, klocp);
    k_vtrans<<<dim3(64, 7, 16), 256, 0, stream>>>(lvp, lvT);
    k_scores<<<dim3(13, 16), 256, 0, stream>>>(lqp, lkp, llocp, klocp, param, attn);
    k_pv<<<dim3(16, 13, 16), 256, 0, stream>>>(attn, lvT, out);
}

// Round 2
// 579.918 us; speedup vs baseline: 1.1412x; 1.1412x over previous
//
#include <hip/hip_runtime.h>
#include <hip/hip_bf16.h>
#include <math.h>

typedef float floatx4 __attribute__((ext_vector_type(4)));
typedef __bf16 bf16x8 __attribute__((ext_vector_type(8)));
typedef unsigned short ushort_t;

__device__ __forceinline__ ushort_t f2bf(float f) {
    union { float f; unsigned int i; } v; v.f = f;
    unsigned int i = v.i;
    return (ushort_t)((i + 0x7FFFu + ((i >> 16) & 1u)) >> 16);  // RNE, inputs finite
}
__device__ __forceinline__ unsigned int pack2(float a, float b) {
    return (unsigned int)f2bf(a) | ((unsigned int)f2bf(b) << 16);
}
__device__ __forceinline__ floatx4 mfma16(bf16x8 a, bf16x8 b, floatx4 c) {
    return __builtin_amdgcn_mfma_f32_16x16x32_bf16(a, b, c, 0, 0, 0);
}
// async global->LDS, 16B per lane; lds base must be wave-uniform, lane i lands at base+i*16
__device__ __forceinline__ void load_lds16(const ushort_t* g, ushort_t* l) {
    __builtin_amdgcn_global_load_lds(
        (const __attribute__((address_space(1))) unsigned int*)g,
        (__attribute__((address_space(3))) unsigned int*)l, 16, 0, 0);
}

// ---------------- fp32 -> bf16 conversion of activations (q,k,v,loc), 3200x2048 each
__global__ __launch_bounds__(256) void k_convert(const float* __restrict__ q, const float* __restrict__ k,
                          const float* __restrict__ v, const float* __restrict__ loc,
                          ushort_t* qb, ushort_t* kb, ushort_t* vb, ushort_t* locb) {
    int z = blockIdx.y;
    const float* src = z == 0 ? q : z == 1 ? k : z == 2 ? v : loc;
    ushort_t* dst    = z == 0 ? qb : z == 1 ? kb : z == 2 ? vb : locb;
    size_t idx = (size_t)blockIdx.x * 256 + threadIdx.x;  // float4 index; grid sized exactly
    floatx4 f = *(const floatx4*)(src + idx * 4);
    uint2 o;
    o.x = pack2(f[0], f[1]);
    o.y = pack2(f[2], f[3]);
    *(uint2*)(dst + idx * 4) = o;
}

// ---------------- Weight transpose+convert: W (2048x2048 fp32, KxN) -> Wt (NxK bf16)
__global__ void k_wtrans(const float* __restrict__ w0, const float* __restrict__ w1,
                         const float* __restrict__ w2, const float* __restrict__ w3,
                         const float* __restrict__ w4,
                         ushort_t* t0, ushort_t* t1, ushort_t* t2, ushort_t* t3, ushort_t* t4) {
    __shared__ float tile[32][33];
    int z = blockIdx.z;
    const float* W = z == 0 ? w0 : z == 1 ? w1 : z == 2 ? w2 : z == 3 ? w3 : w4;
    ushort_t* T    = z == 0 ? t0 : z == 1 ? t1 : z == 2 ? t2 : z == 3 ? t3 : t4;
    int n0 = blockIdx.x * 32, k0 = blockIdx.y * 32;
    int tx = threadIdx.x & 31, ty = threadIdx.x >> 5;  // ty 0..7
#pragma unroll
    for (int i = 0; i < 4; i++) {
        int row = ty + i * 8;
        tile[row][tx] = W[(size_t)(k0 + row) * 2048 + n0 + tx];
    }
    __syncthreads();
#pragma unroll
    for (int i = 0; i < 4; i++) {
        int row = ty + i * 8;
        T[(size_t)(n0 + row) * 2048 + k0 + tx] = f2bf(tile[tx][row]);
    }
}

// ---------------- lv (3200x2048 bf16) -> lvT ([b][h][t] padded t->224, zeros)
__global__ void k_vtrans(const ushort_t* __restrict__ lv, ushort_t* __restrict__ lvT) {
    __shared__ ushort_t tile[32][33];
    int n0 = blockIdx.x * 32;   // H tile
    int t0 = blockIdx.y * 32;   // token tile (224 total)
    int b = blockIdx.z;
    int tx = threadIdx.x & 31, ty = threadIdx.x >> 5;
#pragma unroll
    for (int i = 0; i < 4; i++) {
        int row = ty + i * 8;
        int tk = t0 + row;
        ushort_t v = 0;
        if (tk < 200) v = lv[(size_t)(b * 200 + tk) * 2048 + n0 + tx];
        tile[row][tx] = v;
    }
    __syncthreads();
#pragma unroll
    for (int i = 0; i < 4; i++) {
        int row = ty + i * 8;
        lvT[((size_t)b * 2048 + n0 + row) * 224 + t0 + tx] = tile[tx][row];
    }
}

// ---------------- Batched projection GEMM (m97 structure): C = A(bf16) @ Wt^T + bias, bf16 out
// 128x128 tile, BK=32, global_load_lds width-16 staging, unpadded LDS panels
__global__ __launch_bounds__(256) void k_gemm(
    const ushort_t* A0, const ushort_t* A1, const ushort_t* A2, const ushort_t* A3, const ushort_t* A4,
    const ushort_t* W0, const ushort_t* W1, const ushort_t* W2, const ushort_t* W3, const ushort_t* W4,
    const float* B0, const float* B1, const float* B2, const float* B3, const float* B4,
    ushort_t* C0, ushort_t* C1, ushort_t* C2, ushort_t* C3, ushort_t* C4) {
    int z = blockIdx.z;
    const ushort_t* A  = z == 0 ? A0 : z == 1 ? A1 : z == 2 ? A2 : z == 3 ? A3 : A4;
    const ushort_t* Wt = z == 0 ? W0 : z == 1 ? W1 : z == 2 ? W2 : z == 3 ? W3 : W4;
    const float* bias  = z == 0 ? B0 : z == 1 ? B1 : z == 2 ? B2 : z == 3 ? B3 : B4;
    ushort_t* C        = z == 0 ? C0 : z == 1 ? C1 : z == 2 ? C2 : z == 3 ? C3 : C4;

    const int K = 2048;
    int m0 = blockIdx.x * 128, n0 = blockIdx.y * 128;
    __shared__ ushort_t As[128 * 32];  // UNPADDED: required by global_load_lds lane ordering
    __shared__ ushort_t Bs[128 * 32];
    int tid = threadIdx.x;
    int lane = tid & 63, w = tid >> 6;
    int quad = lane >> 4, col = lane & 15;
    int wr = w >> 1, wc = w & 1;

    // staging: wave w covers rows [w*32, w*32+32), 2 instrs x 1024B each
    int srow0 = w * 32 + (lane >> 2);
    int srow1 = srow0 + 16;
    int skcol = (lane & 3) * 8;
    const ushort_t* Ag0 = A + (size_t)(m0 + srow0) * K + skcol;
    const ushort_t* Ag1 = A + (size_t)(m0 + srow1) * K + skcol;
    const ushort_t* Bg0 = Wt + (size_t)(n0 + srow0) * K + skcol;
    const ushort_t* Bg1 = Wt + (size_t)(n0 + srow1) * K + skcol;
    ushort_t* Asl = As + w * 1024;  // wave-uniform LDS dest (w*2048 bytes)
    ushort_t* Bsl = Bs + w * 1024;

    int aoff[4], boff[4];
#pragma unroll
    for (int i = 0; i < 4; i++) {
        aoff[i] = (wr * 64 + i * 16 + col) * 32 + quad * 8;
        boff[i] = (wc * 64 + i * 16 + col) * 32 + quad * 8;
    }

    floatx4 acc[4][4] = {};

    for (int k0 = 0; k0 < K; k0 += 32) {
        __syncthreads();  // previous iter's ds_reads done before overwrite
        load_lds16(Ag0 + k0, Asl);
        load_lds16(Ag1 + k0, Asl + 512);
        load_lds16(Bg0 + k0, Bsl);
        load_lds16(Bg1 + k0, Bsl + 512);
        __syncthreads();  // staging complete (vmcnt(0) drained at barrier)
        bf16x8 af[4], bfr[4];
#pragma unroll
        for (int i = 0; i < 4; i++) af[i] = *(const bf16x8*)&As[aoff[i]];
#pragma unroll
        for (int i = 0; i < 4; i++) bfr[i] = *(const bf16x8*)&Bs[boff[i]];
#pragma unroll
        for (int mi = 0; mi < 4; mi++)
#pragma unroll
            for (int ni = 0; ni < 4; ni++)
                acc[mi][ni] = mfma16(af[mi], bfr[ni], acc[mi][ni]);
    }

#pragma unroll
    for (int ni = 0; ni < 4; ni++) {
        int n = n0 + wc * 64 + ni * 16 + col;
        float bv = bias[n];
#pragma unroll
        for (int mi = 0; mi < 4; mi++) {
#pragma unroll
            for (int r = 0; r < 4; r++) {
                int m = m0 + wr * 64 + mi * 16 + quad * 4 + r;
                C[(size_t)m * 2048 + n] = f2bf(acc[mi][ni][r] + bv);
            }
        }
    }
}

// ---------------- Scores + softmax -> attn (bf16, [b][200 rows][224 cols], cols>=200 zero)
__global__ __launch_bounds__(256) void k_scores(
    const ushort_t* __restrict__ lq, const ushort_t* __restrict__ lk,
    const ushort_t* __restrict__ lloc, const ushort_t* __restrict__ kloc,
    const float* __restrict__ param, ushort_t* __restrict__ attn) {
    int qt = blockIdx.x;  // 0..12
    int b = blockIdx.y;   // 0..15
    int tid = threadIdx.x;
    int lane = tid & 63, w = tid >> 6;
    int quad = lane >> 4, col = lane & 15;
    int aq = qt * 16 + col; if (aq > 199) aq = 199;
    size_t gq = (size_t)(b * 200 + aq) * 2048;
    size_t gk[4];
#pragma unroll
    for (int i = 0; i < 4; i++) {
        int key = (w + 4 * i) * 16 + col;
        if (key > 199) key = 199;
        gk[i] = (size_t)(b * 200 + key) * 2048;
    }
    floatx4 acc[4] = {};

    for (int k0 = 0; k0 < 2048; k0 += 32) {
        int ko = k0 + quad * 8;
        bf16x8 lqv = *(const bf16x8*)(lq + gq + ko);
        bf16x8 llv = *(const bf16x8*)(lloc + gq + ko);
        floatx4 p0 = *(const floatx4*)(param + gq + ko);
        floatx4 p1 = *(const floatx4*)(param + gq + ko + 4);
        bf16x8 q1, q2;
#pragma unroll
        for (int j = 0; j < 4; j++) {
            q1[j]     = (__bf16)((float)lqv[j] + p0[j]);
            q1[j + 4] = (__bf16)((float)lqv[j + 4] + p1[j]);
            q2[j]     = (__bf16)((float)lqv[j] + (float)llv[j]);
            q2[j + 4] = (__bf16)((float)lqv[j + 4] + (float)llv[j + 4]);
        }
#pragma unroll
        for (int i = 0; i < 4; i++) {
            if (w + 4 * i < 14) {
                bf16x8 kv = *(const bf16x8*)(lk + gk[i] + ko);
                bf16x8 kl = *(const bf16x8*)(kloc + gk[i] + ko);
                acc[i] = mfma16(q1, kv, acc[i]);
                acc[i] = mfma16(q2, kl, acc[i]);
            }
        }
    }

    __shared__ float sc[16][224];
    const float scale = 0.022097086912079608f;  // 1/sqrt(2048)
#pragma unroll
    for (int i = 0; i < 4; i++) {
        int kf = w + 4 * i;
        if (kf < 14) {
#pragma unroll
            for (int r = 0; r < 4; r++) sc[quad * 4 + r][kf * 16 + col] = acc[i][r] * scale;
        }
    }
    __syncthreads();

    int r = tid >> 4, c16 = tid & 15;
    int qrow = qt * 16 + r;
    float ev[14];
    float mx = -1e30f;
#pragma unroll
    for (int j = 0; j < 14; j++) {
        int cc = c16 * 14 + j;
        float v = (cc < 200) ? sc[r][cc] : -1e30f;
        ev[j] = v;
        mx = fmaxf(mx, v);
    }
#pragma unroll
    for (int m = 1; m < 16; m <<= 1) mx = fmaxf(mx, __shfl_xor(mx, m, 16));
    float s = 0.f;
#pragma unroll
    for (int j = 0; j < 14; j++) {
        float e = __expf(ev[j] - mx);
        ev[j] = e;
        s += e;
    }
#pragma unroll
    for (int m = 1; m < 16; m <<= 1) s += __shfl_xor(s, m, 16);
    float rs = 1.0f / s;
    if (qrow < 200) {
        ushort_t* arow = attn + (size_t)(b * 200 + qrow) * 224;
#pragma unroll
        for (int j = 0; j < 14; j++) arow[c16 * 14 + j] = f2bf(ev[j] * rs);
    }
}

// ---------------- out[b][m][n] = attn[b][m][:] @ lv  (via lvT), fp32 out
__global__ __launch_bounds__(256) void k_pv(const ushort_t* __restrict__ attn,
                                            const ushort_t* __restrict__ lvT,
                                            float* __restrict__ out) {
    int nt = blockIdx.x;  // 0..15 (128 cols each)
    int qt = blockIdx.y;  // 0..12 (16 rows each)
    int b = blockIdx.z;
    int tid = threadIdx.x, lane = tid & 63, w = tid >> 6;
    int quad = lane >> 4, col = lane & 15;
    int aq = qt * 16 + col; if (aq > 199) aq = 199;
    const ushort_t* arow = attn + (size_t)(b * 200 + aq) * 224;
    int nbase = nt * 128 + w * 32;
    const ushort_t* bp0 = lvT + ((size_t)b * 2048 + nbase + col) * 224;
    const ushort_t* bp1 = lvT + ((size_t)b * 2048 + nbase + 16 + col) * 224;
    floatx4 acc[2] = {};
#pragma unroll
    for (int k0 = 0; k0 < 224; k0 += 32) {
        int ko = k0 + quad * 8;
        bf16x8 av = *(const bf16x8*)(arow + ko);
        bf16x8 b0 = *(const bf16x8*)(bp0 + ko);
        bf16x8 b1 = *(const bf16x8*)(bp1 + ko);
        acc[0] = mfma16(av, b0, acc[0]);
        acc[1] = mfma16(av, b1, acc[1]);
    }
#pragma unroll
    for (int f = 0; f < 2; f++) {
        int n = nbase + f * 16 + col;
#pragma unroll
        for (int r = 0; r < 4; r++) {
            int m = qt * 16 + quad * 4 + r;
            if (m < 200) out[(size_t)(b * 200 + m) * 2048 + n] = acc[f][r];
        }
    }
}

extern "C" void kernel_launch(void* const* d_in, const int* in_sizes, int n_in,
                              void* d_out, int out_size, void* d_ws, size_t ws_size,
                              hipStream_t stream) {
    (void)in_sizes; (void)n_in; (void)out_size; (void)ws_size;
    const float* q    = (const float*)d_in[0];
    const float* k    = (const float*)d_in[1];
    const float* v    = (const float*)d_in[2];
    const float* loc  = (const float*)d_in[3];
    const float* Wq   = (const float*)d_in[4];
    const float* bq   = (const float*)d_in[5];
    const float* Wk   = (const float*)d_in[6];
    const float* bk   = (const float*)d_in[7];
    const float* Wv   = (const float*)d_in[8];
    const float* bv   = (const float*)d_in[9];
    const float* Wloc = (const float*)d_in[10];
    const float* bloc = (const float*)d_in[11];
    const float* Wlk  = (const float*)d_in[12];
    const float* blk  = (const float*)d_in[13];
    const float* param = (const float*)d_in[14];
    float* out = (float*)d_out;

    // workspace layout (~160 MB): wt region reused for lvT+attn after k_gemm
    size_t off = 0;
    auto nxt = [&](size_t bytes) {
        void* p = (char*)d_ws + off;
        off += (bytes + 255) & ~(size_t)255;
        return p;
    };
    ushort_t* wt[5];
    for (int i = 0; i < 5; i++) wt[i] = (ushort_t*)nxt(2048ull * 2048 * 2);
    ushort_t* qb    = (ushort_t*)nxt(3200ull * 2048 * 2);
    ushort_t* kb    = (ushort_t*)nxt(3200ull * 2048 * 2);
    ushort_t* vb    = (ushort_t*)nxt(3200ull * 2048 * 2);
    ushort_t* locb  = (ushort_t*)nxt(3200ull * 2048 * 2);
    ushort_t* lqp   = (ushort_t*)nxt(3200ull * 2048 * 2);
    ushort_t* lkp   = (ushort_t*)nxt(3200ull * 2048 * 2);
    ushort_t* lvp   = (ushort_t*)nxt(3200ull * 2048 * 2);
    ushort_t* llocp = (ushort_t*)nxt(3200ull * 2048 * 2);
    ushort_t* klocp = (ushort_t*)nxt(3200ull * 2048 * 2);
    // overlay onto dead wt region (41.9 MB >= 14.7+1.5 MB)
    ushort_t* lvT  = wt[0];
    ushort_t* attn = wt[0] + 16ull * 2048 * 224;

    k_convert<<<dim3(6400, 4), 256, 0, stream>>>(q, k, v, loc, qb, kb, vb, locb);
    k_wtrans<<<dim3(64, 64, 5), 256, 0, stream>>>(Wq, Wk, Wv, Wloc, Wlk,
                                                  wt[0], wt[1], wt[2], wt[3], wt[4]);
    k_gemm<<<dim3(25, 16, 5), 256, 0, stream>>>(qb, kb, vb, locb, locb,
                                                wt[0], wt[1], wt[2], wt[3], wt[4],
                                                bq, bk, bv, bloc, blk,
                                                lqp, lkp, lvp, llocp, klocp);
    k_vtrans<<<dim3(64, 7, 16), 256, 0, stream>>>(lvp, lvT);
    k_scores<<<dim3(13, 16), 256, 0, stream>>>(lqp, lkp, llocp, klocp, param, attn);
    k_pv<<<dim3(16, 13, 16), 256, 0, stream>>>(attn, lvT, out);
}

// Round 4
// 550.775 us; speedup vs baseline: 1.2015x; 1.0529x over previous
//
#include <hip/hip_runtime.h>
#include <hip/hip_bf16.h>
#include <math.h>

typedef float floatx4 __attribute__((ext_vector_type(4)));
typedef __bf16 bf16x8 __attribute__((ext_vector_type(8)));
typedef unsigned short ushort_t;

__device__ __forceinline__ ushort_t f2bf(float f) {
    union { float f; unsigned int i; } v; v.f = f;
    unsigned int i = v.i;
    return (ushort_t)((i + 0x7FFFu + ((i >> 16) & 1u)) >> 16);  // RNE, inputs finite
}
__device__ __forceinline__ unsigned int pack2(float a, float b) {
    return (unsigned int)f2bf(a) | ((unsigned int)f2bf(b) << 16);
}
__device__ __forceinline__ floatx4 mfma16(bf16x8 a, bf16x8 b, floatx4 c) {
    return __builtin_amdgcn_mfma_f32_16x16x32_bf16(a, b, c, 0, 0, 0);
}
// async global->LDS, 16B/lane; g is PER-LANE address, lds base wave-uniform,
// lane i lands at lds_base + i*16 bytes
__device__ __forceinline__ void load_lds16(const ushort_t* g, ushort_t* l) {
    __builtin_amdgcn_global_load_lds(
        (const __attribute__((address_space(1))) unsigned int*)g,
        (__attribute__((address_space(3))) unsigned int*)l, 16, 0, 0);
}

// ---------------- fp32 -> bf16 conversion of activations (q,k,v,loc), 3200x2048 each
__global__ __launch_bounds__(256) void k_convert(const float* __restrict__ q, const float* __restrict__ k,
                          const float* __restrict__ v, const float* __restrict__ loc,
                          ushort_t* qb, ushort_t* kb, ushort_t* vb, ushort_t* locb) {
    int z = blockIdx.y;
    const float* src = z == 0 ? q : z == 1 ? k : z == 2 ? v : loc;
    ushort_t* dst    = z == 0 ? qb : z == 1 ? kb : z == 2 ? vb : locb;
    size_t idx = (size_t)blockIdx.x * 256 + threadIdx.x;
    floatx4 f = *(const floatx4*)(src + idx * 4);
    uint2 o;
    o.x = pack2(f[0], f[1]);
    o.y = pack2(f[2], f[3]);
    *(uint2*)(dst + idx * 4) = o;
}

// ---------------- Weight transpose+convert: W (2048x2048 fp32, KxN) -> Wt (NxK bf16)
__global__ void k_wtrans(const float* __restrict__ w0, const float* __restrict__ w1,
                         const float* __restrict__ w2, const float* __restrict__ w3,
                         const float* __restrict__ w4,
                         ushort_t* t0, ushort_t* t1, ushort_t* t2, ushort_t* t3, ushort_t* t4) {
    __shared__ float tile[32][33];
    int z = blockIdx.z;
    const float* W = z == 0 ? w0 : z == 1 ? w1 : z == 2 ? w2 : z == 3 ? w3 : w4;
    ushort_t* T    = z == 0 ? t0 : z == 1 ? t1 : z == 2 ? t2 : z == 3 ? t3 : t4;
    int n0 = blockIdx.x * 32, k0 = blockIdx.y * 32;
    int tx = threadIdx.x & 31, ty = threadIdx.x >> 5;
#pragma unroll
    for (int i = 0; i < 4; i++) {
        int row = ty + i * 8;
        tile[row][tx] = W[(size_t)(k0 + row) * 2048 + n0 + tx];
    }
    __syncthreads();
#pragma unroll
    for (int i = 0; i < 4; i++) {
        int row = ty + i * 8;
        T[(size_t)(n0 + row) * 2048 + k0 + tx] = f2bf(tile[tx][row]);
    }
}

// ---------------- lv (3200x2048 bf16) -> lvT ([b][h][t] padded t->224, zeros)
__global__ void k_vtrans(const ushort_t* __restrict__ lv, ushort_t* __restrict__ lvT) {
    __shared__ ushort_t tile[32][33];
    int n0 = blockIdx.x * 32;
    int t0 = blockIdx.y * 32;
    int b = blockIdx.z;
    int tx = threadIdx.x & 31, ty = threadIdx.x >> 5;
#pragma unroll
    for (int i = 0; i < 4; i++) {
        int row = ty + i * 8;
        int tk = t0 + row;
        ushort_t v = 0;
        if (tk < 200) v = lv[(size_t)(b * 200 + tk) * 2048 + n0 + tx];
        tile[row][tx] = v;
    }
    __syncthreads();
#pragma unroll
    for (int i = 0; i < 4; i++) {
        int row = ty + i * 8;
        lvT[((size_t)b * 2048 + n0 + row) * 224 + t0 + tx] = tile[tx][row];
    }
}

// ---------------- Batched projection GEMM (m97 structure): C = A(bf16) @ Wt^T + bias
// z=0 -> lqp, z=1 -> kcat[:, 0:2048], z=2 -> lvp, z=3 -> llocp, z=4 -> kcat[:, 2048:4096]
__global__ __launch_bounds__(256) void k_gemm(
    const ushort_t* A0, const ushort_t* A1, const ushort_t* A2, const ushort_t* A3, const ushort_t* A4,
    const ushort_t* W0, const ushort_t* W1, const ushort_t* W2, const ushort_t* W3, const ushort_t* W4,
    const float* B0, const float* B1, const float* B2, const float* B3, const float* B4,
    ushort_t* lqp, ushort_t* lvp, ushort_t* llocp, ushort_t* kcat) {
    int z = blockIdx.z;
    const ushort_t* A  = z == 0 ? A0 : z == 1 ? A1 : z == 2 ? A2 : z == 3 ? A3 : A4;
    const ushort_t* Wt = z == 0 ? W0 : z == 1 ? W1 : z == 2 ? W2 : z == 3 ? W3 : W4;
    const float* bias  = z == 0 ? B0 : z == 1 ? B1 : z == 2 ? B2 : z == 3 ? B3 : B4;

    const int K = 2048;
    int m0 = blockIdx.x * 128, n0 = blockIdx.y * 128;
    __shared__ ushort_t As[128 * 32];  // unpadded: global_load_lds lane order
    __shared__ ushort_t Bs[128 * 32];
    int tid = threadIdx.x;
    int lane = tid & 63, w = tid >> 6;
    int quad = lane >> 4, col = lane & 15;
    int wr = w >> 1, wc = w & 1;

    int srow0 = w * 32 + (lane >> 2);
    int srow1 = srow0 + 16;
    int skcol = (lane & 3) * 8;
    const ushort_t* Ag0 = A + (size_t)(m0 + srow0) * K + skcol;
    const ushort_t* Ag1 = A + (size_t)(m0 + srow1) * K + skcol;
    const ushort_t* Bg0 = Wt + (size_t)(n0 + srow0) * K + skcol;
    const ushort_t* Bg1 = Wt + (size_t)(n0 + srow1) * K + skcol;
    ushort_t* Asl = As + w * 1024;
    ushort_t* Bsl = Bs + w * 1024;

    int aoff[4], boff[4];
#pragma unroll
    for (int i = 0; i < 4; i++) {
        aoff[i] = (wr * 64 + i * 16 + col) * 32 + quad * 8;
        boff[i] = (wc * 64 + i * 16 + col) * 32 + quad * 8;
    }

    floatx4 acc[4][4] = {};

    for (int k0 = 0; k0 < K; k0 += 32) {
        __syncthreads();
        load_lds16(Ag0 + k0, Asl);
        load_lds16(Ag1 + k0, Asl + 512);
        load_lds16(Bg0 + k0, Bsl);
        load_lds16(Bg1 + k0, Bsl + 512);
        __syncthreads();
        bf16x8 af[4], bfr[4];
#pragma unroll
        for (int i = 0; i < 4; i++) af[i] = *(const bf16x8*)&As[aoff[i]];
#pragma unroll
        for (int i = 0; i < 4; i++) bfr[i] = *(const bf16x8*)&Bs[boff[i]];
#pragma unroll
        for (int mi = 0; mi < 4; mi++)
#pragma unroll
            for (int ni = 0; ni < 4; ni++)
                acc[mi][ni] = mfma16(af[mi], bfr[ni], acc[mi][ni]);
    }

    ushort_t* Cplain = z == 0 ? lqp : z == 2 ? lvp : llocp;
    int kcoff = (z == 4) ? 2048 : 0;
    bool to_kcat = (z == 1 || z == 4);
#pragma unroll
    for (int ni = 0; ni < 4; ni++) {
        int n = n0 + wc * 64 + ni * 16 + col;
        float bv = bias[n];
#pragma unroll
        for (int mi = 0; mi < 4; mi++) {
#pragma unroll
            for (int r = 0; r < 4; r++) {
                int m = m0 + wr * 64 + mi * 16 + quad * 4 + r;
                ushort_t val = f2bf(acc[mi][ni][r] + bv);
                if (to_kcat) {
                    int b = m / 200, rr = m - b * 200;
                    kcat[((size_t)(b * 224 + rr)) * 4096 + kcoff + n] = val;
                } else {
                    Cplain[(size_t)m * 2048 + n] = val;
                }
            }
        }
    }
}

// ---------------- qcat[b][r][0:2048] = lq + param ; qcat[b][r][2048:] = lq + lloc
__global__ __launch_bounds__(256) void k_qprep(const ushort_t* __restrict__ lqp,
                                               const ushort_t* __restrict__ llocp,
                                               const float* __restrict__ param,
                                               ushort_t* __restrict__ qcat) {
    int m = blockIdx.x;           // 0..3199
    int b = m / 200, r = m - b * 200;
    int c = threadIdx.x * 8;
    bf16x8 ql = *(const bf16x8*)(lqp + (size_t)m * 2048 + c);
    bf16x8 ll = *(const bf16x8*)(llocp + (size_t)m * 2048 + c);
    floatx4 p0 = *(const floatx4*)(param + (size_t)m * 2048 + c);
    floatx4 p1 = *(const floatx4*)(param + (size_t)m * 2048 + c + 4);
    bf16x8 q1, q2;
#pragma unroll
    for (int j = 0; j < 4; j++) {
        q1[j]     = (__bf16)((float)ql[j] + p0[j]);
        q1[j + 4] = (__bf16)((float)ql[j + 4] + p1[j]);
        q2[j]     = (__bf16)((float)ql[j] + (float)ll[j]);
        q2[j + 4] = (__bf16)((float)ql[j + 4] + (float)ll[j + 4]);
    }
    ushort_t* dst = qcat + ((size_t)(b * 224 + r)) * 4096 + c;
    *(bf16x8*)dst = q1;
    *(bf16x8*)(dst + 2048) = q2;
}

// ---------------- Fused scores GEMM + softmax + PV
// grid (7 m-tiles x 16 b), 256 thr. Per block: 32 q-rows x 224 keys, K=4096,
// then softmax, then PV (out 32 x 2048, staging lvT in 128-col chunks).
__global__ __launch_bounds__(256) void k_attn(const ushort_t* __restrict__ qcat,
                                              const ushort_t* __restrict__ kcat,
                                              const ushort_t* __restrict__ lvT,
                                              float* __restrict__ out) {
    int mt = blockIdx.x;   // 0..6
    int b  = blockIdx.y;   // 0..15
    __shared__ ushort_t ab[32 * 224];   // softmaxed P (bf16), cols>=200 zero
    __shared__ ushort_t big[28672];     // 57344 B: QK staging + sc, later vchunk
    ushort_t* As = big;                 // 32x32
    ushort_t* Bs = big + 1024;          // 224x32
    float* sc = (float*)(big + 8192);   // 32x224 fp32 (bytes 16384..45056)
    ushort_t* vchunk = big;             // 128x224

    int tid = threadIdx.x;
    int lane = tid & 63, w = tid >> 6;
    int quad = lane >> 4, col = lane & 15;
    int srow = lane >> 2, scol = (lane & 3) * 8;

    const ushort_t* qbase = qcat + ((size_t)b * 224 + mt * 32) * 4096;
    const ushort_t* kbase = kcat + (size_t)b * 224 * 4096;

    // staging assignment: 16 ops (14 B-panel + 2 A-panel), 4 per wave
    const ushort_t* ssrc[4];
    ushort_t* sdst[4];
#pragma unroll
    for (int o = 0; o < 4; o++) {
        int id = w * 4 + o;
        if (id < 14) {
            ssrc[o] = kbase + (size_t)(id * 16 + srow) * 4096 + scol;
            sdst[o] = Bs + id * 512;
        } else {
            ssrc[o] = qbase + (size_t)((id - 14) * 16 + srow) * 4096 + scol;
            sdst[o] = As + (id - 14) * 512;
        }
    }

    floatx4 acc[2][4] = {};
    for (int k0 = 0; k0 < 4096; k0 += 32) {
        __syncthreads();
#pragma unroll
        for (int o = 0; o < 4; o++) load_lds16(ssrc[o] + k0, sdst[o]);
        __syncthreads();
        bf16x8 af[2];
#pragma unroll
        for (int mi = 0; mi < 2; mi++) af[mi] = *(const bf16x8*)&As[(mi * 16 + col) * 32 + quad * 8];
#pragma unroll
        for (int fi = 0; fi < 4; fi++) {
            int f = w + fi * 4;
            if (f < 14) {
                bf16x8 bf = *(const bf16x8*)&Bs[(f * 16 + col) * 32 + quad * 8];
#pragma unroll
                for (int mi = 0; mi < 2; mi++) acc[mi][fi] = mfma16(af[mi], bf, acc[mi][fi]);
            }
        }
    }

    const float scale2 = 0.022097086912079608f;  // 1/sqrt(2048)
#pragma unroll
    for (int fi = 0; fi < 4; fi++) {
        int f = w + fi * 4;
        if (f < 14) {
#pragma unroll
            for (int mi = 0; mi < 2; mi++)
#pragma unroll
                for (int r = 0; r < 4; r++)
                    sc[(mi * 16 + quad * 4 + r) * 224 + f * 16 + col] = acc[mi][fi][r] * scale2;
        }
    }
    __syncthreads();

    // softmax: 8 threads per row, 28 cols each
    {
        int row = tid >> 3, part = tid & 7;
        int c0 = part * 28;
        float ev[28];
        float mx = -1e30f;
#pragma unroll
        for (int j = 0; j < 28; j++) {
            int c = c0 + j;
            float v = (c < 200) ? sc[row * 224 + c] : -1e30f;
            ev[j] = v;
            mx = fmaxf(mx, v);
        }
#pragma unroll
        for (int m = 1; m < 8; m <<= 1) mx = fmaxf(mx, __shfl_xor(mx, m, 8));
        float s = 0.f;
#pragma unroll
        for (int j = 0; j < 28; j++) {
            float e = __expf(ev[j] - mx);
            ev[j] = e;
            s += e;
        }
#pragma unroll
        for (int m = 1; m < 8; m <<= 1) s += __shfl_xor(s, m, 8);
        float rs = 1.0f / s;
#pragma unroll
        for (int j = 0; j < 28; j++) {
            int c = c0 + j;
            ab[row * 224 + c] = (c < 200) ? f2bf(ev[j] * rs) : (ushort_t)0;
        }
    }
    __syncthreads();

    // PV: out[32 x 2048] in chunks of 128 cols; vchunk aliases QK staging+sc
    const ushort_t* vb_base = lvT + (size_t)b * 2048 * 224;
    for (int nc = 0; nc < 2048; nc += 128) {
        __syncthreads();
        // flat copy of contiguous 57344 B region: 56 ops, 14 per wave, PER-LANE src
        const ushort_t* src0 = vb_base + (size_t)nc * 224;
#pragma unroll
        for (int o = 0; o < 14; o++) {
            int id = w * 14 + o;
            load_lds16(src0 + (size_t)id * 512 + lane * 8, vchunk + id * 512);
        }
        __syncthreads();
        floatx4 pacc[2][2] = {};
#pragma unroll
        for (int k0 = 0; k0 < 224; k0 += 32) {
            bf16x8 paf[2], vbf[2];
#pragma unroll
            for (int mi = 0; mi < 2; mi++) paf[mi] = *(const bf16x8*)&ab[(mi * 16 + col) * 224 + k0 + quad * 8];
#pragma unroll
            for (int j = 0; j < 2; j++) vbf[j] = *(const bf16x8*)&vchunk[(w * 32 + j * 16 + col) * 224 + k0 + quad * 8];
#pragma unroll
            for (int mi = 0; mi < 2; mi++)
#pragma unroll
                for (int j = 0; j < 2; j++) pacc[mi][j] = mfma16(paf[mi], vbf[j], pacc[mi][j]);
        }
#pragma unroll
        for (int mi = 0; mi < 2; mi++) {
#pragma unroll
            for (int j = 0; j < 2; j++) {
                int n = nc + w * 32 + j * 16 + col;
#pragma unroll
                for (int r = 0; r < 4; r++) {
                    int m = mt * 32 + mi * 16 + quad * 4 + r;
                    if (m < 200) out[((size_t)b * 200 + m) * 2048 + n] = pacc[mi][j][r];
                }
            }
        }
    }
}

extern "C" void kernel_launch(void* const* d_in, const int* in_sizes, int n_in,
                              void* d_out, int out_size, void* d_ws, size_t ws_size,
                              hipStream_t stream) {
    (void)in_sizes; (void)n_in; (void)out_size; (void)ws_size;
    const float* q    = (const float*)d_in[0];
    const float* k    = (const float*)d_in[1];
    const float* v    = (const float*)d_in[2];
    const float* loc  = (const float*)d_in[3];
    const float* Wq   = (const float*)d_in[4];
    const float* bq   = (const float*)d_in[5];
    const float* Wk   = (const float*)d_in[6];
    const float* bk   = (const float*)d_in[7];
    const float* Wv   = (const float*)d_in[8];
    const float* bv   = (const float*)d_in[9];
    const float* Wloc = (const float*)d_in[10];
    const float* bloc = (const float*)d_in[11];
    const float* Wlk  = (const float*)d_in[12];
    const float* blk  = (const float*)d_in[13];
    const float* param = (const float*)d_in[14];
    float* out = (float*)d_out;

    size_t off = 0;
    auto nxt = [&](size_t bytes) {
        void* p = (char*)d_ws + off;
        off += (bytes + 255) & ~(size_t)255;
        return p;
    };
    ushort_t* wt[5];
    for (int i = 0; i < 5; i++) wt[i] = (ushort_t*)nxt(2048ull * 2048 * 2);
    ushort_t* qb    = (ushort_t*)nxt(3200ull * 2048 * 2);
    ushort_t* kb    = (ushort_t*)nxt(3200ull * 2048 * 2);
    ushort_t* vb    = (ushort_t*)nxt(3200ull * 2048 * 2);
    ushort_t* locb  = (ushort_t*)nxt(3200ull * 2048 * 2);
    ushort_t* lqp   = (ushort_t*)nxt(3200ull * 2048 * 2);
    ushort_t* llocp = (ushort_t*)nxt(3200ull * 2048 * 2);
    ushort_t* lvp   = (ushort_t*)nxt(3200ull * 2048 * 2);
    ushort_t* kcat  = (ushort_t*)nxt(16ull * 224 * 4096 * 2);
    // overlays (dead regions after k_gemm):
    ushort_t* lvT  = wt[0];  // 14.7 MB into 41.9 MB wt region
    ushort_t* qcat = qb;     // 29.4 MB into 52.4 MB conv region (qb..vb contiguous)

    k_convert<<<dim3(6400, 4), 256, 0, stream>>>(q, k, v, loc, qb, kb, vb, locb);
    k_wtrans<<<dim3(64, 64, 5), 256, 0, stream>>>(Wq, Wk, Wv, Wloc, Wlk,
                                                  wt[0], wt[1], wt[2], wt[3], wt[4]);
    k_gemm<<<dim3(25, 16, 5), 256, 0, stream>>>(qb, kb, vb, locb, locb,
                                                wt[0], wt[1], wt[2], wt[3], wt[4],
                                                bq, bk, bv, bloc, blk,
                                                lqp, lvp, llocp, kcat);
    k_qprep<<<dim3(3200), 256, 0, stream>>>(lqp, llocp, param, qcat);
    k_vtrans<<<dim3(64, 7, 16), 256, 0, stream>>>(lvp, lvT);
    k_attn<<<dim3(7, 16), 256, 0, stream>>>(qcat, kcat, lvT, out);
}

// Round 5
// 493.310 us; speedup vs baseline: 1.3415x; 1.1165x over previous
//
#include <hip/hip_runtime.h>
#include <hip/hip_bf16.h>
#include <math.h>

typedef float floatx4 __attribute__((ext_vector_type(4)));
typedef __bf16 bf16x8 __attribute__((ext_vector_type(8)));
typedef unsigned short ushort_t;

__device__ __forceinline__ ushort_t f2bf(float f) {
    union { float f; unsigned int i; } v; v.f = f;
    unsigned int i = v.i;
    return (ushort_t)((i + 0x7FFFu + ((i >> 16) & 1u)) >> 16);  // RNE, inputs finite
}
__device__ __forceinline__ unsigned int pack2(float a, float b) {
    return (unsigned int)f2bf(a) | ((unsigned int)f2bf(b) << 16);
}
__device__ __forceinline__ floatx4 mfma16(bf16x8 a, bf16x8 b, floatx4 c) {
    return __builtin_amdgcn_mfma_f32_16x16x32_bf16(a, b, c, 0, 0, 0);
}
// async global->LDS, 16B/lane; g is PER-LANE address, lds base wave-uniform,
// lane i lands at lds_base + i*16 bytes
__device__ __forceinline__ void load_lds16(const ushort_t* g, ushort_t* l) {
    __builtin_amdgcn_global_load_lds(
        (const __attribute__((address_space(1))) unsigned int*)g,
        (__attribute__((address_space(3))) unsigned int*)l, 16, 0, 0);
}

// ---------------- fp32 -> bf16 conversion of activations (q,k,v,loc), 3200x2048 each
__global__ __launch_bounds__(256) void k_convert(const float* __restrict__ q, const float* __restrict__ k,
                          const float* __restrict__ v, const float* __restrict__ loc,
                          ushort_t* qb, ushort_t* kb, ushort_t* vb, ushort_t* locb) {
    int z = blockIdx.y;
    const float* src = z == 0 ? q : z == 1 ? k : z == 2 ? v : loc;
    ushort_t* dst    = z == 0 ? qb : z == 1 ? kb : z == 2 ? vb : locb;
    size_t idx = (size_t)blockIdx.x * 256 + threadIdx.x;
    floatx4 f = *(const floatx4*)(src + idx * 4);
    uint2 o;
    o.x = pack2(f[0], f[1]);
    o.y = pack2(f[2], f[3]);
    *(uint2*)(dst + idx * 4) = o;
}

// ---------------- Weight transpose+convert: W (2048x2048 fp32, KxN) -> Wt (NxK bf16)
__global__ void k_wtrans(const float* __restrict__ w0, const float* __restrict__ w1,
                         const float* __restrict__ w2, const float* __restrict__ w3,
                         const float* __restrict__ w4,
                         ushort_t* t0, ushort_t* t1, ushort_t* t2, ushort_t* t3, ushort_t* t4) {
    __shared__ float tile[32][33];
    int z = blockIdx.z;
    const float* W = z == 0 ? w0 : z == 1 ? w1 : z == 2 ? w2 : z == 3 ? w3 : w4;
    ushort_t* T    = z == 0 ? t0 : z == 1 ? t1 : z == 2 ? t2 : z == 3 ? t3 : t4;
    int n0 = blockIdx.x * 32, k0 = blockIdx.y * 32;
    int tx = threadIdx.x & 31, ty = threadIdx.x >> 5;
#pragma unroll
    for (int i = 0; i < 4; i++) {
        int row = ty + i * 8;
        tile[row][tx] = W[(size_t)(k0 + row) * 2048 + n0 + tx];
    }
    __syncthreads();
#pragma unroll
    for (int i = 0; i < 4; i++) {
        int row = ty + i * 8;
        T[(size_t)(n0 + row) * 2048 + k0 + tx] = f2bf(tile[tx][row]);
    }
}

// ---------------- lv (3200x2048 bf16) -> lvT ([b][h][t] padded t->224, zeros)
__global__ void k_vtrans(const ushort_t* __restrict__ lv, ushort_t* __restrict__ lvT) {
    __shared__ ushort_t tile[32][33];
    int n0 = blockIdx.x * 32;
    int t0 = blockIdx.y * 32;
    int b = blockIdx.z;
    int tx = threadIdx.x & 31, ty = threadIdx.x >> 5;
#pragma unroll
    for (int i = 0; i < 4; i++) {
        int row = ty + i * 8;
        int tk = t0 + row;
        ushort_t v = 0;
        if (tk < 200) v = lv[(size_t)(b * 200 + tk) * 2048 + n0 + tx];
        tile[row][tx] = v;
    }
    __syncthreads();
#pragma unroll
    for (int i = 0; i < 4; i++) {
        int row = ty + i * 8;
        lvT[((size_t)b * 2048 + n0 + row) * 224 + t0 + tx] = tile[tx][row];
    }
}

// ---------------- Batched projection GEMM, BK=64 (two 32-K half-panels per barrier pair)
// z=0 -> lqp, z=1 -> kcat[:, 0:2048], z=2 -> lvp, z=3 -> llocp, z=4 -> kcat[:, 2048:4096]
__global__ __launch_bounds__(256) void k_gemm(
    const ushort_t* A0, const ushort_t* A1, const ushort_t* A2, const ushort_t* A3, const ushort_t* A4,
    const ushort_t* W0, const ushort_t* W1, const ushort_t* W2, const ushort_t* W3, const ushort_t* W4,
    const float* B0, const float* B1, const float* B2, const float* B3, const float* B4,
    ushort_t* lqp, ushort_t* lvp, ushort_t* llocp, ushort_t* kcat) {
    int z = blockIdx.z;
    const ushort_t* A  = z == 0 ? A0 : z == 1 ? A1 : z == 2 ? A2 : z == 3 ? A3 : A4;
    const ushort_t* Wt = z == 0 ? W0 : z == 1 ? W1 : z == 2 ? W2 : z == 3 ? W3 : W4;
    const float* bias  = z == 0 ? B0 : z == 1 ? B1 : z == 2 ? B2 : z == 3 ? B3 : B4;

    const int K = 2048;
    int m0 = blockIdx.x * 128, n0 = blockIdx.y * 128;
    __shared__ ushort_t As[2][128 * 32];  // unpadded: global_load_lds lane order
    __shared__ ushort_t Bs[2][128 * 32];
    int tid = threadIdx.x;
    int lane = tid & 63, w = tid >> 6;
    int quad = lane >> 4, col = lane & 15;
    int wr = w >> 1, wc = w & 1;

    int srow0 = w * 32 + (lane >> 2);
    int srow1 = srow0 + 16;
    int skcol = (lane & 3) * 8;
    const ushort_t* Ag0 = A + (size_t)(m0 + srow0) * K + skcol;
    const ushort_t* Ag1 = A + (size_t)(m0 + srow1) * K + skcol;
    const ushort_t* Bg0 = Wt + (size_t)(n0 + srow0) * K + skcol;
    const ushort_t* Bg1 = Wt + (size_t)(n0 + srow1) * K + skcol;
    ushort_t* Asl0 = As[0] + w * 1024;
    ushort_t* Asl1 = As[1] + w * 1024;
    ushort_t* Bsl0 = Bs[0] + w * 1024;
    ushort_t* Bsl1 = Bs[1] + w * 1024;

    int aoff[4], boff[4];
#pragma unroll
    for (int i = 0; i < 4; i++) {
        aoff[i] = (wr * 64 + i * 16 + col) * 32 + quad * 8;
        boff[i] = (wc * 64 + i * 16 + col) * 32 + quad * 8;
    }

    floatx4 acc[4][4] = {};

    for (int k0 = 0; k0 < K; k0 += 64) {
        __syncthreads();
        load_lds16(Ag0 + k0, Asl0);
        load_lds16(Ag1 + k0, Asl0 + 512);
        load_lds16(Bg0 + k0, Bsl0);
        load_lds16(Bg1 + k0, Bsl0 + 512);
        load_lds16(Ag0 + k0 + 32, Asl1);
        load_lds16(Ag1 + k0 + 32, Asl1 + 512);
        load_lds16(Bg0 + k0 + 32, Bsl1);
        load_lds16(Bg1 + k0 + 32, Bsl1 + 512);
        __syncthreads();
#pragma unroll
        for (int h = 0; h < 2; h++) {
            bf16x8 af[4], bfr[4];
#pragma unroll
            for (int i = 0; i < 4; i++) af[i] = *(const bf16x8*)&As[h][aoff[i]];
#pragma unroll
            for (int i = 0; i < 4; i++) bfr[i] = *(const bf16x8*)&Bs[h][boff[i]];
#pragma unroll
            for (int mi = 0; mi < 4; mi++)
#pragma unroll
                for (int ni = 0; ni < 4; ni++)
                    acc[mi][ni] = mfma16(af[mi], bfr[ni], acc[mi][ni]);
        }
    }

    ushort_t* Cplain = z == 0 ? lqp : z == 2 ? lvp : llocp;
    int kcoff = (z == 4) ? 2048 : 0;
    bool to_kcat = (z == 1 || z == 4);
    float bvv[4];
#pragma unroll
    for (int ni = 0; ni < 4; ni++) bvv[ni] = bias[n0 + wc * 64 + ni * 16 + col];
#pragma unroll
    for (int mi = 0; mi < 4; mi++) {
#pragma unroll
        for (int r = 0; r < 4; r++) {
            int m = m0 + wr * 64 + mi * 16 + quad * 4 + r;
            ushort_t* crow;
            if (to_kcat) {
                int bb = m / 200, rr = m - bb * 200;
                crow = kcat + (size_t)(bb * 224 + rr) * 4096 + kcoff;
            } else {
                crow = Cplain + (size_t)m * 2048;
            }
#pragma unroll
            for (int ni = 0; ni < 4; ni++) {
                int n = n0 + wc * 64 + ni * 16 + col;
                crow[n] = f2bf(acc[mi][ni][r] + bvv[ni]);
            }
        }
    }
}

// ---------------- qcat[b][r][0:2048] = lq + param ; qcat[b][r][2048:] = lq + lloc
__global__ __launch_bounds__(256) void k_qprep(const ushort_t* __restrict__ lqp,
                                               const ushort_t* __restrict__ llocp,
                                               const float* __restrict__ param,
                                               ushort_t* __restrict__ qcat) {
    int m = blockIdx.x;           // 0..3199
    int b = m / 200, r = m - b * 200;
    int c = threadIdx.x * 8;
    bf16x8 ql = *(const bf16x8*)(lqp + (size_t)m * 2048 + c);
    bf16x8 ll = *(const bf16x8*)(llocp + (size_t)m * 2048 + c);
    floatx4 p0 = *(const floatx4*)(param + (size_t)m * 2048 + c);
    floatx4 p1 = *(const floatx4*)(param + (size_t)m * 2048 + c + 4);
    bf16x8 q1, q2;
#pragma unroll
    for (int j = 0; j < 4; j++) {
        q1[j]     = (__bf16)((float)ql[j] + p0[j]);
        q1[j + 4] = (__bf16)((float)ql[j + 4] + p1[j]);
        q2[j]     = (__bf16)((float)ql[j] + (float)ll[j]);
        q2[j + 4] = (__bf16)((float)ql[j + 4] + (float)ll[j + 4]);
    }
    ushort_t* dst = qcat + ((size_t)(b * 224 + r)) * 4096 + c;
    *(bf16x8*)dst = q1;
    *(bf16x8*)(dst + 2048) = q2;
}

// ---------------- Scores (K-split): part[kc][b][row 0..223][key 0..223] fp32 partial
// grid (7 qt x 16 b x 2 kc), 256 thr; 32 q-rows x 224 keys, K=2048 per block
__global__ __launch_bounds__(256) void k_scores(const ushort_t* __restrict__ qcat,
                                                const ushort_t* __restrict__ kcat,
                                                float* __restrict__ part) {
    int qt = blockIdx.x;   // 0..6
    int b  = blockIdx.y;   // 0..15
    int kc = blockIdx.z;   // 0..1
    __shared__ ushort_t As[32 * 32];    // 2 KB
    __shared__ ushort_t Bs[224 * 32];   // 14 KB

    int tid = threadIdx.x;
    int lane = tid & 63, w = tid >> 6;
    int quad = lane >> 4, col = lane & 15;
    int srow = lane >> 2, scol = (lane & 3) * 8;

    const ushort_t* qbase = qcat + ((size_t)b * 224 + qt * 32) * 4096 + kc * 2048;
    const ushort_t* kbase = kcat + (size_t)b * 224 * 4096 + kc * 2048;

    const ushort_t* ssrc[4];
    ushort_t* sdst[4];
#pragma unroll
    for (int o = 0; o < 4; o++) {
        int id = w * 4 + o;
        if (id < 14) {
            ssrc[o] = kbase + (size_t)(id * 16 + srow) * 4096 + scol;
            sdst[o] = Bs + id * 512;
        } else {
            ssrc[o] = qbase + (size_t)((id - 14) * 16 + srow) * 4096 + scol;
            sdst[o] = As + (id - 14) * 512;
        }
    }

    floatx4 acc[2][4] = {};
    for (int k0 = 0; k0 < 2048; k0 += 32) {
        __syncthreads();
#pragma unroll
        for (int o = 0; o < 4; o++) load_lds16(ssrc[o] + k0, sdst[o]);
        __syncthreads();
        bf16x8 af[2];
#pragma unroll
        for (int mi = 0; mi < 2; mi++) af[mi] = *(const bf16x8*)&As[(mi * 16 + col) * 32 + quad * 8];
#pragma unroll
        for (int fi = 0; fi < 4; fi++) {
            int f = w + fi * 4;
            if (f < 14) {
                bf16x8 bf = *(const bf16x8*)&Bs[(f * 16 + col) * 32 + quad * 8];
#pragma unroll
                for (int mi = 0; mi < 2; mi++) acc[mi][fi] = mfma16(af[mi], bf, acc[mi][fi]);
            }
        }
    }

    float* pbase = part + ((size_t)(kc * 16 + b) * 224 + qt * 32) * 224;
#pragma unroll
    for (int fi = 0; fi < 4; fi++) {
        int f = w + fi * 4;
        if (f < 14) {
#pragma unroll
            for (int mi = 0; mi < 2; mi++)
#pragma unroll
                for (int r = 0; r < 4; r++)
                    pbase[(mi * 16 + quad * 4 + r) * 224 + f * 16 + col] = acc[mi][fi][r];
        }
    }
}

// ---------------- softmax over summed partials -> attn bf16 [b][200][224], cols>=200 zero
// grid 400 blocks x 256 thr; 8 rows/block, 32 threads/row, 7 cols/thread
__global__ __launch_bounds__(256) void k_softmax(const float* __restrict__ part,
                                                 ushort_t* __restrict__ attn) {
    int row = blockIdx.x * 8 + (threadIdx.x >> 5);  // 0..3199
    int b = row / 200, r = row - b * 200;
    int p = threadIdx.x & 31;
    const float* p0 = part + ((size_t)b * 224 + r) * 224;
    const float* p1 = p0 + (size_t)16 * 224 * 224;
    const float scale = 0.022097086912079608f;  // 1/sqrt(2048)
    float ev[7];
    float mx = -1e30f;
#pragma unroll
    for (int j = 0; j < 7; j++) {
        int c = p * 7 + j;
        float v = (c < 200) ? (p0[c] + p1[c]) * scale : -1e30f;
        ev[j] = v;
        mx = fmaxf(mx, v);
    }
#pragma unroll
    for (int m = 1; m < 32; m <<= 1) mx = fmaxf(mx, __shfl_xor(mx, m, 32));
    float s = 0.f;
#pragma unroll
    for (int j = 0; j < 7; j++) {
        float e = __expf(ev[j] - mx);
        ev[j] = e;
        s += e;
    }
#pragma unroll
    for (int m = 1; m < 32; m <<= 1) s += __shfl_xor(s, m, 32);
    float rs = 1.0f / s;
    ushort_t* arow = attn + (size_t)row * 224;
#pragma unroll
    for (int j = 0; j < 7; j++) {
        int c = p * 7 + j;
        arow[c] = (c < 200) ? f2bf(ev[j] * rs) : (ushort_t)0;
    }
}

// ---------------- out[b][m][n] = attn[b][m][:] @ lv  (via lvT), fp32 out
__global__ __launch_bounds__(256) void k_pv(const ushort_t* __restrict__ attn,
                                            const ushort_t* __restrict__ lvT,
                                            float* __restrict__ out) {
    int nt = blockIdx.x;  // 0..15 (128 cols each)
    int qt = blockIdx.y;  // 0..12 (16 rows each)
    int b = blockIdx.z;
    int tid = threadIdx.x, lane = tid & 63, w = tid >> 6;
    int quad = lane >> 4, col = lane & 15;
    int aq = qt * 16 + col; if (aq > 199) aq = 199;
    const ushort_t* arow = attn + (size_t)(b * 200 + aq) * 224;
    int nbase = nt * 128 + w * 32;
    const ushort_t* bp0 = lvT + ((size_t)b * 2048 + nbase + col) * 224;
    const ushort_t* bp1 = lvT + ((size_t)b * 2048 + nbase + 16 + col) * 224;
    floatx4 acc[2] = {};
#pragma unroll
    for (int k0 = 0; k0 < 224; k0 += 32) {
        int ko = k0 + quad * 8;
        bf16x8 av = *(const bf16x8*)(arow + ko);
        bf16x8 b0 = *(const bf16x8*)(bp0 + ko);
        bf16x8 b1 = *(const bf16x8*)(bp1 + ko);
        acc[0] = mfma16(av, b0, acc[0]);
        acc[1] = mfma16(av, b1, acc[1]);
    }
#pragma unroll
    for (int f = 0; f < 2; f++) {
        int n = nbase + f * 16 + col;
#pragma unroll
        for (int r = 0; r < 4; r++) {
            int m = qt * 16 + quad * 4 + r;
            if (m < 200) out[(size_t)(b * 200 + m) * 2048 + n] = acc[f][r];
        }
    }
}

extern "C" void kernel_launch(void* const* d_in, const int* in_sizes, int n_in,
                              void* d_out, int out_size, void* d_ws, size_t ws_size,
                              hipStream_t stream) {
    (void)in_sizes; (void)n_in; (void)out_size; (void)ws_size;
    const float* q    = (const float*)d_in[0];
    const float* k    = (const float*)d_in[1];
    const float* v    = (const float*)d_in[2];
    const float* loc  = (const float*)d_in[3];
    const float* Wq   = (const float*)d_in[4];
    const float* bq   = (const float*)d_in[5];
    const float* Wk   = (const float*)d_in[6];
    const float* bk   = (const float*)d_in[7];
    const float* Wv   = (const float*)d_in[8];
    const float* bv   = (const float*)d_in[9];
    const float* Wloc = (const float*)d_in[10];
    const float* bloc = (const float*)d_in[11];
    const float* Wlk  = (const float*)d_in[12];
    const float* blk  = (const float*)d_in[13];
    const float* param = (const float*)d_in[14];
    float* out = (float*)d_out;

    size_t off = 0;
    auto nxt = [&](size_t bytes) {
        void* p = (char*)d_ws + off;
        off += (bytes + 255) & ~(size_t)255;
        return p;
    };
    ushort_t* wt[5];
    for (int i = 0; i < 5; i++) wt[i] = (ushort_t*)nxt(2048ull * 2048 * 2);
    ushort_t* qb    = (ushort_t*)nxt(3200ull * 2048 * 2);
    ushort_t* kb    = (ushort_t*)nxt(3200ull * 2048 * 2);
    ushort_t* vb    = (ushort_t*)nxt(3200ull * 2048 * 2);
    ushort_t* locb  = (ushort_t*)nxt(3200ull * 2048 * 2);
    ushort_t* lqp   = (ushort_t*)nxt(3200ull * 2048 * 2);
    ushort_t* llocp = (ushort_t*)nxt(3200ull * 2048 * 2);
    ushort_t* lvp   = (ushort_t*)nxt(3200ull * 2048 * 2);
    ushort_t* kcat  = (ushort_t*)nxt(16ull * 224 * 4096 * 2);
    // overlays (wt region = 41.9 MB, dead after k_gemm):
    ushort_t* lvT  = wt[0];                               // bytes 0 .. 14.7 MB
    ushort_t* attn = wt[0] + 16ull * 2048 * 224;          // 14.7 .. 16.1 MB
    float*    part = (float*)((char*)d_ws + 2ull * 2048 * 2048 * 2);  // 16.8 .. 23.2 MB (wt[2]+)
    ushort_t* qcat = qb;   // 29.4 MB into 52.4 MB conv region

    k_convert<<<dim3(6400, 4), 256, 0, stream>>>(q, k, v, loc, qb, kb, vb, locb);
    k_wtrans<<<dim3(64, 64, 5), 256, 0, stream>>>(Wq, Wk, Wv, Wloc, Wlk,
                                                  wt[0], wt[1], wt[2], wt[3], wt[4]);
    k_gemm<<<dim3(25, 16, 5), 256, 0, stream>>>(qb, kb, vb, locb, locb,
                                                wt[0], wt[1], wt[2], wt[3], wt[4],
                                                bq, bk, bv, bloc, blk,
                                                lqp, lvp, llocp, kcat);
    k_qprep<<<dim3(3200), 256, 0, stream>>>(lqp, llocp, param, qcat);
    k_vtrans<<<dim3(64, 7, 16), 256, 0, stream>>>(lvp, lvT);
    k_scores<<<dim3(7, 16, 2), 256, 0, stream>>>(qcat, kcat, part);
    k_softmax<<<dim3(400), 256, 0, stream>>>(part, attn);
    k_pv<<<dim3(16, 13, 16), 256, 0, stream>>>(attn, lvT, out);
}